// Round 1
// baseline (668.005 us; speedup 1.0000x reference)
//
#include <hip/hip_runtime.h>
#include <hip/hip_bf16.h>
#include <cstdint>
#include <cstddef>

#define NPIX   262144      // B*V*D*H*W = 2*1*32*64*64
#define SPAT   131072      // D*H*W (1<<17)
#define NQ     5000
#define NQTOT  20000       // 4*5000
#define NTOT   (NPIX + NQTOT)
#define NCLS   4
#define KSEL   512
#define NROW   4096        // 2*4*512 anchors
#define DIMF   128

// ---- workspace layout (bytes) ----
#define XA_OFF    0u               // 4096*128*4 = 2097152
#define M_OFF     2097152u         // 4096*4
#define NEG_OFF   2113536u         // 4096*4
#define PART_OFF  2129920u         // 4096*8*2*4 = 262144
#define SRC_OFF   2392064u         // 4096*4
#define ZERO_OFF  2408448u
#define P_OFF     2408448u         // 4096*4
#define HA_OFF    2424832u         // 8*2048*4
#define HB_OFF    2490368u         // 8*2048*4
#define HC_OFF    2555904u         // 8*1024*4
#define ST_OFF    2588672u         // 8*8*4
#define EQ_OFF    2588928u         // 8*4096*4 -> ends 2720000
#define ZERO_WORDS 77888u          // (2720000-2408448)/4

// state[p*8 + k]: 0=prefix, 1=krem, 2=threshold, 3=take_eq, 4=gt_cnt, 5=eq_cnt

__global__ void k_zero(unsigned* z) {
    unsigned i = blockIdx.x * blockDim.x + threadIdx.x;
    if (i < ZERO_WORDS) z[i] = 0u;
}

__device__ __forceinline__ void elem_info(int i, const int* lab, const float* ps, const float* qs,
                                          int& p, unsigned& key, unsigned& id) {
    if (i < NPIX) {
        p = lab[i];
        key = __float_as_uint(ps[i]);
        id = (unsigned)i;
    } else {
        int e = i - NPIX;
        int c = e / NQ;
        p = 4 + c;
        key = __float_as_uint(qs[e]);
        id = (unsigned)(e - c * NQ);
    }
}

__global__ void k_hist(const int* __restrict__ lab, const float* __restrict__ ps,
                       const float* __restrict__ qs, const unsigned* __restrict__ st,
                       unsigned* __restrict__ hist, int level) {
    int i = blockIdx.x * blockDim.x + threadIdx.x;
    if (i >= NTOT) return;
    int p; unsigned key, id;
    elem_info(i, lab, ps, qs, p, key, id);
    if (level == 0) {
        atomicAdd(&hist[p * 2048 + (key >> 21)], 1u);
    } else if (level == 1) {
        if ((key >> 21) == (st[p * 8 + 0] >> 21))
            atomicAdd(&hist[p * 2048 + ((key >> 10) & 2047u)], 1u);
    } else {
        if ((key >> 10) == (st[p * 8 + 0] >> 10))
            atomicAdd(&hist[p * 1024 + (key & 1023u)], 1u);
    }
}

__global__ void k_scan(const unsigned* __restrict__ hist, unsigned* __restrict__ st,
                       int nbins, int shift, int level) {
    __shared__ unsigned sh[2048];
    __shared__ unsigned segsum[256];
    int p = blockIdx.x;
    int tid = threadIdx.x;
    const unsigned* h = hist + p * nbins;
    int seg = nbins >> 8;
    for (int i = tid; i < nbins; i += 256) sh[i] = h[i];
    __syncthreads();
    unsigned ssum = 0;
    for (int k = 0; k < seg; ++k) ssum += sh[tid * seg + k];
    segsum[tid] = ssum;
    __syncthreads();
    if (tid == 0) {
        unsigned K = (level == 0) ? (unsigned)KSEL : st[p * 8 + 1];
        unsigned cum = 0;
        int s = 255;
        for (; s > 0; --s) { if (cum + segsum[s] >= K) break; cum += segsum[s]; }
        int b = s * seg + seg - 1;
        for (; b > s * seg; --b) { if (cum + sh[b] >= K) break; cum += sh[b]; }
        unsigned krem = (K > cum) ? (K - cum) : 1u;
        if (level == 0)      { st[p * 8 + 0] = ((unsigned)b) << shift; st[p * 8 + 1] = krem; }
        else if (level == 1) { st[p * 8 + 0] |= ((unsigned)b) << shift; st[p * 8 + 1] = krem; }
        else                 { st[p * 8 + 2] = st[p * 8 + 0] | (unsigned)b; st[p * 8 + 3] = krem; }
    }
}

__global__ void k_gather(const int* __restrict__ lab, const float* __restrict__ ps,
                         const float* __restrict__ qs, unsigned* __restrict__ st,
                         unsigned* __restrict__ src, unsigned* __restrict__ eq) {
    int i = blockIdx.x * blockDim.x + threadIdx.x;
    if (i >= NTOT) return;
    int p; unsigned key, id;
    elem_info(i, lab, ps, qs, p, key, id);
    unsigned T = st[p * 8 + 2];
    if (key > T) {
        unsigned slot = atomicAdd(&st[p * 8 + 4], 1u);
        if (slot < KSEL) src[p * KSEL + slot] = id;
    } else if (key == T) {
        unsigned e = atomicAdd(&st[p * 8 + 5], 1u);
        if (e < 4096u) eq[p * 4096 + e] = id;
    }
}

__global__ void k_eqsel(unsigned* __restrict__ st, unsigned* __restrict__ src,
                        unsigned* __restrict__ eq) {
    int p = blockIdx.x;
    if (threadIdx.x != 0) return;
    unsigned take = st[p * 8 + 3];
    unsigned cnt  = st[p * 8 + 4];
    unsigned m    = st[p * 8 + 5]; if (m > 4096u) m = 4096u;
    unsigned* eb = eq + p * 4096;
    for (unsigned k = 0; k < take; ++k) {
        unsigned best = 0xFFFFFFFFu; int bi = -1;
        for (unsigned t = 0; t < m; ++t) if (eb[t] < best) { best = eb[t]; bi = (int)t; }
        if (bi < 0) break;
        eb[bi] = 0xFFFFFFFFu;
        if (cnt + k < KSEL) src[p * KSEL + cnt + k] = best;
    }
}

__global__ void k_copy(const unsigned* __restrict__ src, const float* __restrict__ feats,
                       const float* __restrict__ pq, float* __restrict__ Xa) {
    int row = blockIdx.x;
    int ch = threadIdx.x;
    unsigned s = src[row];
    float v;
    if (row < 2048) {
        s &= (NPIX - 1);                      // safety clamp (no-op when logic correct)
        unsigned bv = s >> 17, r = s & (SPAT - 1);
        v = feats[((size_t)bv * DIMF + ch) * SPAT + r];
    } else {
        if (s >= NQ) s = NQ - 1;              // safety clamp
        int c = (row - 2048) >> 9;
        v = pq[((size_t)(c * NQ + s)) * DIMF + ch];
    }
    Xa[(size_t)row * DIMF + ch] = v;
}

// ---- pass 1: online row-max + pos/neg exp sums over full 4096x4096 gram ----
__global__ __launch_bounds__(256) void k_pass1(const float* __restrict__ Xa, float* __restrict__ part) {
    __shared__ float shA[2 * 64 * 67];
    __shared__ float shB[64 * 67];
    int row0 = blockIdx.x * 64;
    int col0 = blockIdx.y * 512;
    int tid = threadIdx.x;
    for (int idx = tid; idx < 64 * 64; idx += 256) {
        int r = idx >> 6, k = idx & 63;
        shA[r * 67 + k]           = Xa[(row0 + r) * DIMF + k];
        shA[64 * 67 + r * 67 + k] = Xa[(row0 + r) * DIMF + 64 + k];
    }
    int tr = tid >> 4, tc = tid & 15;
    float mM[4], sn[4], sp[4];
    int gri[4], cli[4];
#pragma unroll
    for (int r = 0; r < 4; ++r) {
        mM[r] = -1e30f; sn[r] = 0.f; sp[r] = 0.f;
        gri[r] = row0 + tr * 4 + r;
        cli[r] = (gri[r] >> 9) & 3;
    }
    for (int ch = 0; ch < 8; ++ch) {
        int c0 = col0 + ch * 64;
        float acc[4][4];
#pragma unroll
        for (int r = 0; r < 4; ++r)
#pragma unroll
            for (int c = 0; c < 4; ++c) acc[r][c] = 0.f;
        for (int h = 0; h < 2; ++h) {
            __syncthreads();
            for (int idx = tid; idx < 64 * 64; idx += 256) {
                int r = idx >> 6, k = idx & 63;
                shB[r * 67 + k] = Xa[(c0 + r) * DIMF + h * 64 + k];
            }
            __syncthreads();
            const float* As = shA + h * (64 * 67) + (tr * 4) * 67;
            const float* Bs = shB + (tc * 4) * 67;
#pragma unroll 8
            for (int k = 0; k < 64; ++k) {
                float a0 = As[k], a1 = As[k + 67], a2 = As[k + 134], a3 = As[k + 201];
                float b0 = Bs[k], b1 = Bs[k + 67], b2 = Bs[k + 134], b3 = Bs[k + 201];
                acc[0][0] = fmaf(a0, b0, acc[0][0]);
                acc[0][1] = fmaf(a0, b1, acc[0][1]);
                acc[0][2] = fmaf(a0, b2, acc[0][2]);
                acc[0][3] = fmaf(a0, b3, acc[0][3]);
                acc[1][0] = fmaf(a1, b0, acc[1][0]);
                acc[1][1] = fmaf(a1, b1, acc[1][1]);
                acc[1][2] = fmaf(a1, b2, acc[1][2]);
                acc[1][3] = fmaf(a1, b3, acc[1][3]);
                acc[2][0] = fmaf(a2, b0, acc[2][0]);
                acc[2][1] = fmaf(a2, b1, acc[2][1]);
                acc[2][2] = fmaf(a2, b2, acc[2][2]);
                acc[2][3] = fmaf(a2, b3, acc[2][3]);
                acc[3][0] = fmaf(a3, b0, acc[3][0]);
                acc[3][1] = fmaf(a3, b1, acc[3][1]);
                acc[3][2] = fmaf(a3, b2, acc[3][2]);
                acc[3][3] = fmaf(a3, b3, acc[3][3]);
            }
        }
#pragma unroll
        for (int r = 0; r < 4; ++r) {
#pragma unroll
            for (int c = 0; c < 4; ++c) {
                int gc = c0 + tc * 4 + c;
                float s = acc[r][c] * 10.0f;   // / TEMPERATURE
                bool pos = (((gc >> 9) & 3) == cli[r]) && (gc != gri[r]);
                if (s > mM[r]) {
                    float f = __expf(mM[r] - s);
                    sn[r] *= f; sp[r] *= f; mM[r] = s;
                }
                float e = __expf(s - mM[r]);
                if (pos) sp[r] += e; else sn[r] += e;
            }
        }
    }
    __syncthreads();
    float* red = shB;   // 64*16*2 floats
#pragma unroll
    for (int r = 0; r < 4; ++r) {
        int lr = tr * 4 + r;
        red[(lr * 16 + tc) * 2 + 0] = mM[r];
        red[(lr * 16 + tc) * 2 + 1] = sn[r];
    }
    __syncthreads();
    // note: sp is only needed transiently for max-rescaling; neg sums (sn) are
    // accumulated directly (no SA-SP cancellation), so only (m, sn) reduce out.
    if (tid < 64) {
        float M = -1e30f;
        for (int t = 0; t < 16; ++t) M = fmaxf(M, red[(tid * 16 + t) * 2]);
        float SN = 0.f;
        for (int t = 0; t < 16; ++t) {
            float f = __expf(red[(tid * 16 + t) * 2] - M);
            SN += red[(tid * 16 + t) * 2 + 1] * f;
        }
        float* o = part + ((size_t)(row0 + tid) * 8 + blockIdx.y) * 2;
        o[0] = M; o[1] = SN;
    }
}

__global__ void k_reduce1(const float* __restrict__ part, float* __restrict__ Mv,
                          float* __restrict__ Ng) {
    int i = blockIdx.x * blockDim.x + threadIdx.x;
    if (i >= NROW) return;
    float M = -1e30f;
    for (int k = 0; k < 8; ++k) M = fmaxf(M, part[((size_t)i * 8 + k) * 2]);
    float SN = 0.f;
    for (int k = 0; k < 8; ++k) {
        float f = __expf(part[((size_t)i * 8 + k) * 2] - M);
        SN += part[((size_t)i * 8 + k) * 2 + 1] * f;
    }
    Mv[i] = M;
    Ng[i] = SN;
}

// ---- pass 2: positives only (same-class 1024 cols per row) ----
__global__ __launch_bounds__(256) void k_pass2(const float* __restrict__ Xa,
                                               const float* __restrict__ Mv,
                                               const float* __restrict__ Ng,
                                               float* __restrict__ P) {
    __shared__ float shA[2 * 64 * 67];
    __shared__ float shB[64 * 67];
    int row0 = blockIdx.x * 64;
    int cls = (row0 >> 9) & 3;
    int col0 = (blockIdx.y ? 2048 : 0) + cls * 512;
    int tid = threadIdx.x;
    for (int idx = tid; idx < 64 * 64; idx += 256) {
        int r = idx >> 6, k = idx & 63;
        shA[r * 67 + k]           = Xa[(row0 + r) * DIMF + k];
        shA[64 * 67 + r * 67 + k] = Xa[(row0 + r) * DIMF + 64 + k];
    }
    int tr = tid >> 4, tc = tid & 15;
    float mi[4], ngi[4], pac[4];
    int gri[4];
#pragma unroll
    for (int r = 0; r < 4; ++r) {
        gri[r] = row0 + tr * 4 + r;
        mi[r] = Mv[gri[r]];
        ngi[r] = Ng[gri[r]];
        pac[r] = 0.f;
    }
    for (int ch = 0; ch < 8; ++ch) {
        int c0 = col0 + ch * 64;
        float acc[4][4];
#pragma unroll
        for (int r = 0; r < 4; ++r)
#pragma unroll
            for (int c = 0; c < 4; ++c) acc[r][c] = 0.f;
        for (int h = 0; h < 2; ++h) {
            __syncthreads();
            for (int idx = tid; idx < 64 * 64; idx += 256) {
                int r = idx >> 6, k = idx & 63;
                shB[r * 67 + k] = Xa[(c0 + r) * DIMF + h * 64 + k];
            }
            __syncthreads();
            const float* As = shA + h * (64 * 67) + (tr * 4) * 67;
            const float* Bs = shB + (tc * 4) * 67;
#pragma unroll 8
            for (int k = 0; k < 64; ++k) {
                float a0 = As[k], a1 = As[k + 67], a2 = As[k + 134], a3 = As[k + 201];
                float b0 = Bs[k], b1 = Bs[k + 67], b2 = Bs[k + 134], b3 = Bs[k + 201];
                acc[0][0] = fmaf(a0, b0, acc[0][0]);
                acc[0][1] = fmaf(a0, b1, acc[0][1]);
                acc[0][2] = fmaf(a0, b2, acc[0][2]);
                acc[0][3] = fmaf(a0, b3, acc[0][3]);
                acc[1][0] = fmaf(a1, b0, acc[1][0]);
                acc[1][1] = fmaf(a1, b1, acc[1][1]);
                acc[1][2] = fmaf(a1, b2, acc[1][2]);
                acc[1][3] = fmaf(a1, b3, acc[1][3]);
                acc[2][0] = fmaf(a2, b0, acc[2][0]);
                acc[2][1] = fmaf(a2, b1, acc[2][1]);
                acc[2][2] = fmaf(a2, b2, acc[2][2]);
                acc[2][3] = fmaf(a2, b3, acc[2][3]);
                acc[3][0] = fmaf(a3, b0, acc[3][0]);
                acc[3][1] = fmaf(a3, b1, acc[3][1]);
                acc[3][2] = fmaf(a3, b2, acc[3][2]);
                acc[3][3] = fmaf(a3, b3, acc[3][3]);
            }
        }
#pragma unroll
        for (int r = 0; r < 4; ++r) {
#pragma unroll
            for (int c = 0; c < 4; ++c) {
                int gc = c0 + tc * 4 + c;
                if (gc != gri[r]) {
                    float t = acc[r][c] * 10.0f - mi[r];
                    pac[r] += t - __logf(__expf(t) + ngi[r] + 1e-10f);
                }
            }
        }
    }
    __syncthreads();
    float* red = shB;   // 64*16 floats
#pragma unroll
    for (int r = 0; r < 4; ++r) red[(tr * 4 + r) * 16 + tc] = pac[r];
    __syncthreads();
    if (tid < 64) {
        float s = 0.f;
        for (int t = 0; t < 16; ++t) s += red[tid * 16 + t];
        atomicAdd(&P[row0 + tid], s);
    }
}

__global__ void k_final(const float* __restrict__ P, float* __restrict__ out) {
    __shared__ float sh[256];
    int tid = threadIdx.x;
    float s = 0.f;
    for (int i = tid; i < NROW; i += 256) s += P[i];
    sh[tid] = s;
    __syncthreads();
    for (int off = 128; off > 0; off >>= 1) {
        if (tid < off) sh[tid] += sh[tid + off];
        __syncthreads();
    }
    if (tid == 0) out[0] = -(10.0f / 7.0f) * sh[0] / (1023.0f * (float)NROW);
}

extern "C" void kernel_launch(void* const* d_in, const int* in_sizes, int n_in,
                              void* d_out, int out_size, void* d_ws, size_t ws_size,
                              hipStream_t stream) {
    const float* feats = (const float*)d_in[0];
    const int*   lab   = (const int*)d_in[1];
    const float* pq    = (const float*)d_in[2];
    const float* ps    = (const float*)d_in[3];
    const float* qs    = (const float*)d_in[4];
    float* out = (float*)d_out;
    char* ws = (char*)d_ws;

    float*    Xa  = (float*)(ws + XA_OFF);
    float*    Mv  = (float*)(ws + M_OFF);
    float*    Ng  = (float*)(ws + NEG_OFF);
    float*    Pt  = (float*)(ws + PART_OFF);
    unsigned* src = (unsigned*)(ws + SRC_OFF);
    float*    Pv  = (float*)(ws + P_OFF);
    unsigned* hA  = (unsigned*)(ws + HA_OFF);
    unsigned* hB  = (unsigned*)(ws + HB_OFF);
    unsigned* hC  = (unsigned*)(ws + HC_OFF);
    unsigned* st  = (unsigned*)(ws + ST_OFF);
    unsigned* eq  = (unsigned*)(ws + EQ_OFF);

    k_zero<<<(ZERO_WORDS + 255) / 256, 256, 0, stream>>>((unsigned*)(ws + ZERO_OFF));

    int hb = (NTOT + 255) / 256;
    k_hist<<<hb, 256, 0, stream>>>(lab, ps, qs, st, hA, 0);
    k_scan<<<8, 256, 0, stream>>>(hA, st, 2048, 21, 0);
    k_hist<<<hb, 256, 0, stream>>>(lab, ps, qs, st, hB, 1);
    k_scan<<<8, 256, 0, stream>>>(hB, st, 2048, 10, 1);
    k_hist<<<hb, 256, 0, stream>>>(lab, ps, qs, st, hC, 2);
    k_scan<<<8, 256, 0, stream>>>(hC, st, 1024, 0, 2);
    k_gather<<<hb, 256, 0, stream>>>(lab, ps, qs, st, src, eq);
    k_eqsel<<<8, 64, 0, stream>>>(st, src, eq);
    k_copy<<<NROW, 128, 0, stream>>>(src, feats, pq, Xa);

    k_pass1<<<dim3(64, 8), 256, 0, stream>>>(Xa, Pt);
    k_reduce1<<<16, 256, 0, stream>>>(Pt, Mv, Ng);
    k_pass2<<<dim3(64, 2), 256, 0, stream>>>(Xa, Mv, Ng, Pv);
    k_final<<<1, 256, 0, stream>>>(Pv, out);
}

// Round 2
// 475.711 us; speedup vs baseline: 1.4042x; 1.4042x over previous
//
#include <hip/hip_runtime.h>
#include <hip/hip_bf16.h>
#include <cstdint>
#include <cstddef>

#define NPIX   262144      // B*V*D*H*W = 2*1*32*64*64
#define SPAT   131072      // D*H*W (1<<17)
#define NQ     5000
#define NQTOT  20000       // 4*5000
#define NTOT   (NPIX + NQTOT)
#define NCLS   4
#define KSEL   512
#define NROW   4096        // 2*4*512 anchors
#define DIMF   128
#define HBLK   64          // histogram blocks

// ---- workspace layout (bytes) ----
#define XA_OFF    0u               // 4096*128*4 = 2097152
#define M_OFF     2097152u         // 4096*4
#define NEG_OFF   2113536u         // 4096*4
#define PART_OFF  2129920u         // 4096*8*2*4 = 262144
#define SRC_OFF   2392064u         // 4096*4
#define ZERO_OFF  2408448u
#define P_OFF     2408448u         // 4096*4
#define HA_OFF    2424832u         // 8*2048*4
#define HB_OFF    2490368u         // 8*2048*4
#define HC_OFF    2555904u         // 8*1024*4
#define ST_OFF    2588672u         // 8*8*4
#define EQ_OFF    2588928u         // 8*4096*4 -> ends 2720000
#define ZERO_WORDS 77888u          // (2720000-2408448)/4

// state[p*8 + k]: 0=prefix, 1=krem, 2=threshold, 3=take_eq, 4=gt_cnt, 5=eq_cnt

__global__ void k_zero(unsigned* z) {
    unsigned i = blockIdx.x * blockDim.x + threadIdx.x;
    if (i < ZERO_WORDS) z[i] = 0u;
}

__device__ __forceinline__ void elem_info(int i, const int* lab, const float* ps, const float* qs,
                                          int& p, unsigned& key, unsigned& id) {
    if (i < NPIX) {
        p = lab[i];
        key = __float_as_uint(ps[i]);
        id = (unsigned)i;
    } else {
        int e = i - NPIX;
        int c = e / NQ;
        p = 4 + c;
        key = __float_as_uint(qs[e]);
        id = (unsigned)(e - c * NQ);
    }
}

// LDS-privatized histogram: uniform scores collapse the radix digit onto a
// handful of bins -> global atomics serialized at ~2cyc/op (222us measured).
// Per-block LDS hist + merge-nonzero drops that to LDS-atomic speed.
__global__ __launch_bounds__(256) void k_hist(const int* __restrict__ lab,
                       const float* __restrict__ ps,
                       const float* __restrict__ qs, const unsigned* __restrict__ st,
                       unsigned* __restrict__ hist, int level) {
    __shared__ unsigned lh[8 * 2048];
    int tid = threadIdx.x;
    for (int i = tid; i < 8 * 2048; i += 256) lh[i] = 0u;
    __syncthreads();
    for (int i = blockIdx.x * 256 + tid; i < NTOT; i += HBLK * 256) {
        int p; unsigned key, id;
        elem_info(i, lab, ps, qs, p, key, id);
        if (level == 0) {
            atomicAdd(&lh[p * 2048 + (key >> 21)], 1u);
        } else if (level == 1) {
            if ((key >> 21) == (st[p * 8 + 0] >> 21))
                atomicAdd(&lh[p * 2048 + ((key >> 10) & 2047u)], 1u);
        } else {
            if ((key >> 10) == (st[p * 8 + 0] >> 10))
                atomicAdd(&lh[p * 1024 + (key & 1023u)], 1u);
        }
    }
    __syncthreads();
    int nb = (level == 2) ? 8 * 1024 : 8 * 2048;
    for (int i = tid; i < nb; i += 256) {
        unsigned v = lh[i];
        if (v) atomicAdd(&hist[i], v);
    }
}

__global__ void k_scan(const unsigned* __restrict__ hist, unsigned* __restrict__ st,
                       int nbins, int shift, int level) {
    __shared__ unsigned sh[2048];
    __shared__ unsigned segsum[256];
    int p = blockIdx.x;
    int tid = threadIdx.x;
    const unsigned* h = hist + p * nbins;
    int seg = nbins >> 8;
    for (int i = tid; i < nbins; i += 256) sh[i] = h[i];
    __syncthreads();
    unsigned ssum = 0;
    for (int k = 0; k < seg; ++k) ssum += sh[tid * seg + k];
    segsum[tid] = ssum;
    __syncthreads();
    if (tid == 0) {
        unsigned K = (level == 0) ? (unsigned)KSEL : st[p * 8 + 1];
        unsigned cum = 0;
        int s = 255;
        for (; s > 0; --s) { if (cum + segsum[s] >= K) break; cum += segsum[s]; }
        int b = s * seg + seg - 1;
        for (; b > s * seg; --b) { if (cum + sh[b] >= K) break; cum += sh[b]; }
        unsigned krem = (K > cum) ? (K - cum) : 1u;
        if (level == 0)      { st[p * 8 + 0] = ((unsigned)b) << shift; st[p * 8 + 1] = krem; }
        else if (level == 1) { st[p * 8 + 0] |= ((unsigned)b) << shift; st[p * 8 + 1] = krem; }
        else                 { st[p * 8 + 2] = st[p * 8 + 0] | (unsigned)b; st[p * 8 + 3] = krem; }
    }
}

__global__ void k_gather(const int* __restrict__ lab, const float* __restrict__ ps,
                         const float* __restrict__ qs, unsigned* __restrict__ st,
                         unsigned* __restrict__ src, unsigned* __restrict__ eq) {
    int i = blockIdx.x * blockDim.x + threadIdx.x;
    if (i >= NTOT) return;
    int p; unsigned key, id;
    elem_info(i, lab, ps, qs, p, key, id);
    unsigned T = st[p * 8 + 2];
    if (key > T) {
        unsigned slot = atomicAdd(&st[p * 8 + 4], 1u);
        if (slot < KSEL) src[p * KSEL + slot] = id;
    } else if (key == T) {
        unsigned e = atomicAdd(&st[p * 8 + 5], 1u);
        if (e < 4096u) eq[p * 4096 + e] = id;
    }
}

__global__ void k_eqsel(unsigned* __restrict__ st, unsigned* __restrict__ src,
                        unsigned* __restrict__ eq) {
    int p = blockIdx.x;
    if (threadIdx.x != 0) return;
    unsigned take = st[p * 8 + 3];
    unsigned cnt  = st[p * 8 + 4];
    unsigned m    = st[p * 8 + 5]; if (m > 4096u) m = 4096u;
    unsigned* eb = eq + p * 4096;
    for (unsigned k = 0; k < take; ++k) {
        unsigned best = 0xFFFFFFFFu; int bi = -1;
        for (unsigned t = 0; t < m; ++t) if (eb[t] < best) { best = eb[t]; bi = (int)t; }
        if (bi < 0) break;
        eb[bi] = 0xFFFFFFFFu;
        if (cnt + k < KSEL) src[p * KSEL + cnt + k] = best;
    }
}

__global__ void k_copy(const unsigned* __restrict__ src, const float* __restrict__ feats,
                       const float* __restrict__ pq, float* __restrict__ Xa) {
    int row = blockIdx.x;
    int ch = threadIdx.x;
    unsigned s = src[row];
    float v;
    if (row < 2048) {
        s &= (NPIX - 1);                      // safety clamp (no-op when logic correct)
        unsigned bv = s >> 17, r = s & (SPAT - 1);
        v = feats[((size_t)bv * DIMF + ch) * SPAT + r];
    } else {
        if (s >= NQ) s = NQ - 1;              // safety clamp
        int c = (row - 2048) >> 9;
        v = pq[((size_t)(c * NQ + s)) * DIMF + ch];
    }
    Xa[(size_t)row * DIMF + ch] = v;
}

// ---- pass 1: online row-max + pos/neg exp sums over full 4096x4096 gram ----
__global__ __launch_bounds__(256) void k_pass1(const float* __restrict__ Xa, float* __restrict__ part) {
    __shared__ float shA[2 * 64 * 67];
    __shared__ float shB[64 * 67];
    int row0 = blockIdx.x * 64;
    int col0 = blockIdx.y * 512;
    int tid = threadIdx.x;
    for (int idx = tid; idx < 64 * 64; idx += 256) {
        int r = idx >> 6, k = idx & 63;
        shA[r * 67 + k]           = Xa[(row0 + r) * DIMF + k];
        shA[64 * 67 + r * 67 + k] = Xa[(row0 + r) * DIMF + 64 + k];
    }
    int tr = tid >> 4, tc = tid & 15;
    float mM[4], sn[4], sp[4];
    int gri[4], cli[4];
#pragma unroll
    for (int r = 0; r < 4; ++r) {
        mM[r] = -1e30f; sn[r] = 0.f; sp[r] = 0.f;
        gri[r] = row0 + tr * 4 + r;
        cli[r] = (gri[r] >> 9) & 3;
    }
    for (int ch = 0; ch < 8; ++ch) {
        int c0 = col0 + ch * 64;
        float acc[4][4];
#pragma unroll
        for (int r = 0; r < 4; ++r)
#pragma unroll
            for (int c = 0; c < 4; ++c) acc[r][c] = 0.f;
        for (int h = 0; h < 2; ++h) {
            __syncthreads();
            for (int idx = tid; idx < 64 * 64; idx += 256) {
                int r = idx >> 6, k = idx & 63;
                shB[r * 67 + k] = Xa[(c0 + r) * DIMF + h * 64 + k];
            }
            __syncthreads();
            const float* As = shA + h * (64 * 67) + (tr * 4) * 67;
            const float* Bs = shB + (tc * 4) * 67;
#pragma unroll 8
            for (int k = 0; k < 64; ++k) {
                float a0 = As[k], a1 = As[k + 67], a2 = As[k + 134], a3 = As[k + 201];
                float b0 = Bs[k], b1 = Bs[k + 67], b2 = Bs[k + 134], b3 = Bs[k + 201];
                acc[0][0] = fmaf(a0, b0, acc[0][0]);
                acc[0][1] = fmaf(a0, b1, acc[0][1]);
                acc[0][2] = fmaf(a0, b2, acc[0][2]);
                acc[0][3] = fmaf(a0, b3, acc[0][3]);
                acc[1][0] = fmaf(a1, b0, acc[1][0]);
                acc[1][1] = fmaf(a1, b1, acc[1][1]);
                acc[1][2] = fmaf(a1, b2, acc[1][2]);
                acc[1][3] = fmaf(a1, b3, acc[1][3]);
                acc[2][0] = fmaf(a2, b0, acc[2][0]);
                acc[2][1] = fmaf(a2, b1, acc[2][1]);
                acc[2][2] = fmaf(a2, b2, acc[2][2]);
                acc[2][3] = fmaf(a2, b3, acc[2][3]);
                acc[3][0] = fmaf(a3, b0, acc[3][0]);
                acc[3][1] = fmaf(a3, b1, acc[3][1]);
                acc[3][2] = fmaf(a3, b2, acc[3][2]);
                acc[3][3] = fmaf(a3, b3, acc[3][3]);
            }
        }
#pragma unroll
        for (int r = 0; r < 4; ++r) {
#pragma unroll
            for (int c = 0; c < 4; ++c) {
                int gc = c0 + tc * 4 + c;
                float s = acc[r][c] * 10.0f;   // / TEMPERATURE
                bool pos = (((gc >> 9) & 3) == cli[r]) && (gc != gri[r]);
                if (s > mM[r]) {
                    float f = __expf(mM[r] - s);
                    sn[r] *= f; sp[r] *= f; mM[r] = s;
                }
                float e = __expf(s - mM[r]);
                if (pos) sp[r] += e; else sn[r] += e;
            }
        }
    }
    __syncthreads();
    float* red = shB;   // 64*16*2 floats
#pragma unroll
    for (int r = 0; r < 4; ++r) {
        int lr = tr * 4 + r;
        red[(lr * 16 + tc) * 2 + 0] = mM[r];
        red[(lr * 16 + tc) * 2 + 1] = sn[r];
    }
    __syncthreads();
    if (tid < 64) {
        float M = -1e30f;
        for (int t = 0; t < 16; ++t) M = fmaxf(M, red[(tid * 16 + t) * 2]);
        float SN = 0.f;
        for (int t = 0; t < 16; ++t) {
            float f = __expf(red[(tid * 16 + t) * 2] - M);
            SN += red[(tid * 16 + t) * 2 + 1] * f;
        }
        float* o = part + ((size_t)(row0 + tid) * 8 + blockIdx.y) * 2;
        o[0] = M; o[1] = SN;
    }
}

__global__ void k_reduce1(const float* __restrict__ part, float* __restrict__ Mv,
                          float* __restrict__ Ng) {
    int i = blockIdx.x * blockDim.x + threadIdx.x;
    if (i >= NROW) return;
    float M = -1e30f;
    for (int k = 0; k < 8; ++k) M = fmaxf(M, part[((size_t)i * 8 + k) * 2]);
    float SN = 0.f;
    for (int k = 0; k < 8; ++k) {
        float f = __expf(part[((size_t)i * 8 + k) * 2] - M);
        SN += part[((size_t)i * 8 + k) * 2 + 1] * f;
    }
    Mv[i] = M;
    Ng[i] = SN;
}

// ---- pass 2: positives only (same-class 1024 cols per row) ----
__global__ __launch_bounds__(256) void k_pass2(const float* __restrict__ Xa,
                                               const float* __restrict__ Mv,
                                               const float* __restrict__ Ng,
                                               float* __restrict__ P) {
    __shared__ float shA[2 * 64 * 67];
    __shared__ float shB[64 * 67];
    int row0 = blockIdx.x * 64;
    int cls = (row0 >> 9) & 3;
    int col0 = (blockIdx.y ? 2048 : 0) + cls * 512;
    int tid = threadIdx.x;
    for (int idx = tid; idx < 64 * 64; idx += 256) {
        int r = idx >> 6, k = idx & 63;
        shA[r * 67 + k]           = Xa[(row0 + r) * DIMF + k];
        shA[64 * 67 + r * 67 + k] = Xa[(row0 + r) * DIMF + 64 + k];
    }
    int tr = tid >> 4, tc = tid & 15;
    float mi[4], ngi[4], pac[4];
    int gri[4];
#pragma unroll
    for (int r = 0; r < 4; ++r) {
        gri[r] = row0 + tr * 4 + r;
        mi[r] = Mv[gri[r]];
        ngi[r] = Ng[gri[r]];
        pac[r] = 0.f;
    }
    for (int ch = 0; ch < 8; ++ch) {
        int c0 = col0 + ch * 64;
        float acc[4][4];
#pragma unroll
        for (int r = 0; r < 4; ++r)
#pragma unroll
            for (int c = 0; c < 4; ++c) acc[r][c] = 0.f;
        for (int h = 0; h < 2; ++h) {
            __syncthreads();
            for (int idx = tid; idx < 64 * 64; idx += 256) {
                int r = idx >> 6, k = idx & 63;
                shB[r * 67 + k] = Xa[(c0 + r) * DIMF + h * 64 + k];
            }
            __syncthreads();
            const float* As = shA + h * (64 * 67) + (tr * 4) * 67;
            const float* Bs = shB + (tc * 4) * 67;
#pragma unroll 8
            for (int k = 0; k < 64; ++k) {
                float a0 = As[k], a1 = As[k + 67], a2 = As[k + 134], a3 = As[k + 201];
                float b0 = Bs[k], b1 = Bs[k + 67], b2 = Bs[k + 134], b3 = Bs[k + 201];
                acc[0][0] = fmaf(a0, b0, acc[0][0]);
                acc[0][1] = fmaf(a0, b1, acc[0][1]);
                acc[0][2] = fmaf(a0, b2, acc[0][2]);
                acc[0][3] = fmaf(a0, b3, acc[0][3]);
                acc[1][0] = fmaf(a1, b0, acc[1][0]);
                acc[1][1] = fmaf(a1, b1, acc[1][1]);
                acc[1][2] = fmaf(a1, b2, acc[1][2]);
                acc[1][3] = fmaf(a1, b3, acc[1][3]);
                acc[2][0] = fmaf(a2, b0, acc[2][0]);
                acc[2][1] = fmaf(a2, b1, acc[2][1]);
                acc[2][2] = fmaf(a2, b2, acc[2][2]);
                acc[2][3] = fmaf(a2, b3, acc[2][3]);
                acc[3][0] = fmaf(a3, b0, acc[3][0]);
                acc[3][1] = fmaf(a3, b1, acc[3][1]);
                acc[3][2] = fmaf(a3, b2, acc[3][2]);
                acc[3][3] = fmaf(a3, b3, acc[3][3]);
            }
        }
#pragma unroll
        for (int r = 0; r < 4; ++r) {
#pragma unroll
            for (int c = 0; c < 4; ++c) {
                int gc = c0 + tc * 4 + c;
                if (gc != gri[r]) {
                    float t = acc[r][c] * 10.0f - mi[r];
                    pac[r] += t - __logf(__expf(t) + ngi[r] + 1e-10f);
                }
            }
        }
    }
    __syncthreads();
    float* red = shB;   // 64*16 floats
#pragma unroll
    for (int r = 0; r < 4; ++r) red[(tr * 4 + r) * 16 + tc] = pac[r];
    __syncthreads();
    if (tid < 64) {
        float s = 0.f;
        for (int t = 0; t < 16; ++t) s += red[tid * 16 + t];
        atomicAdd(&P[row0 + tid], s);
    }
}

__global__ void k_final(const float* __restrict__ P, float* __restrict__ out) {
    __shared__ float sh[256];
    int tid = threadIdx.x;
    float s = 0.f;
    for (int i = tid; i < NROW; i += 256) s += P[i];
    sh[tid] = s;
    __syncthreads();
    for (int off = 128; off > 0; off >>= 1) {
        if (tid < off) sh[tid] += sh[tid + off];
        __syncthreads();
    }
    if (tid == 0) out[0] = -(10.0f / 7.0f) * sh[0] / (1023.0f * (float)NROW);
}

extern "C" void kernel_launch(void* const* d_in, const int* in_sizes, int n_in,
                              void* d_out, int out_size, void* d_ws, size_t ws_size,
                              hipStream_t stream) {
    const float* feats = (const float*)d_in[0];
    const int*   lab   = (const int*)d_in[1];
    const float* pq    = (const float*)d_in[2];
    const float* ps    = (const float*)d_in[3];
    const float* qs    = (const float*)d_in[4];
    float* out = (float*)d_out;
    char* ws = (char*)d_ws;

    float*    Xa  = (float*)(ws + XA_OFF);
    float*    Mv  = (float*)(ws + M_OFF);
    float*    Ng  = (float*)(ws + NEG_OFF);
    float*    Pt  = (float*)(ws + PART_OFF);
    unsigned* src = (unsigned*)(ws + SRC_OFF);
    float*    Pv  = (float*)(ws + P_OFF);
    unsigned* hA  = (unsigned*)(ws + HA_OFF);
    unsigned* hB  = (unsigned*)(ws + HB_OFF);
    unsigned* hC  = (unsigned*)(ws + HC_OFF);
    unsigned* st  = (unsigned*)(ws + ST_OFF);
    unsigned* eq  = (unsigned*)(ws + EQ_OFF);

    k_zero<<<(ZERO_WORDS + 255) / 256, 256, 0, stream>>>((unsigned*)(ws + ZERO_OFF));

    int hb = (NTOT + 255) / 256;
    k_hist<<<HBLK, 256, 0, stream>>>(lab, ps, qs, st, hA, 0);
    k_scan<<<8, 256, 0, stream>>>(hA, st, 2048, 21, 0);
    k_hist<<<HBLK, 256, 0, stream>>>(lab, ps, qs, st, hB, 1);
    k_scan<<<8, 256, 0, stream>>>(hB, st, 2048, 10, 1);
    k_hist<<<HBLK, 256, 0, stream>>>(lab, ps, qs, st, hC, 2);
    k_scan<<<8, 256, 0, stream>>>(hC, st, 1024, 0, 2);
    k_gather<<<hb, 256, 0, stream>>>(lab, ps, qs, st, src, eq);
    k_eqsel<<<8, 64, 0, stream>>>(st, src, eq);
    k_copy<<<NROW, 128, 0, stream>>>(src, feats, pq, Xa);

    k_pass1<<<dim3(64, 8), 256, 0, stream>>>(Xa, Pt);
    k_reduce1<<<16, 256, 0, stream>>>(Pt, Mv, Ng);
    k_pass2<<<dim3(64, 2), 256, 0, stream>>>(Xa, Mv, Ng, Pv);
    k_final<<<1, 256, 0, stream>>>(Pv, out);
}

// Round 3
// 330.198 us; speedup vs baseline: 2.0230x; 1.4407x over previous
//
#include <hip/hip_runtime.h>
#include <hip/hip_bf16.h>
#include <cstdint>
#include <cstddef>

#define NPIX   262144      // B*V*D*H*W = 2*1*32*64*64
#define SPAT   131072      // D*H*W (1<<17)
#define NQ     5000
#define NQTOT  20000       // 4*5000
#define NTOT   (NPIX + NQTOT)
#define NCLS   4
#define KSEL   512
#define NROW   4096        // 2*4*512 anchors
#define DIMF   128
#define HBLK   64          // histogram blocks

typedef short short8 __attribute__((ext_vector_type(8)));
typedef float f32x4  __attribute__((ext_vector_type(4)));

// ---- workspace layout (bytes) ----
#define XAB_OFF   0u               // bf16 anchors: 4096*128*2 = 1048576
#define M_OFF     1048576u         // 4096*4
#define NEG_OFF   1064960u         // 4096*4
#define PART_OFF  1081344u         // 4096*32*2*4 = 1048576
#define SRC_OFF   2129920u         // 4096*4
#define PSUM_OFF  2146304u         // 256 (zeroed)
#define HA_OFF    2146560u         // 8*2048*4 (zeroed)
#define HB_OFF    2212096u         // 8*2048*4 (zeroed)
#define HC_OFF    2277632u         // 8*1024*4 (zeroed)
#define ST_OFF    2310400u         // 8*8*4    (zeroed)
#define EQ_OFF    2310656u         // 8*4096*4 (zeroed) -> ends 2441728
#define ZERO_WORDS 73856u          // (2441728-2146304)/4

// state[p*8 + k]: 0=prefix, 1=krem, 2=threshold, 3=take_eq, 4=gt_cnt, 5=eq_cnt

__global__ void k_zero(unsigned* z) {
    unsigned i = blockIdx.x * blockDim.x + threadIdx.x;
    if (i < ZERO_WORDS) z[i] = 0u;
}

__device__ __forceinline__ void elem_info(int i, const int* lab, const float* ps, const float* qs,
                                          int& p, unsigned& key, unsigned& id) {
    if (i < NPIX) {
        p = lab[i];
        key = __float_as_uint(ps[i]);
        id = (unsigned)i;
    } else {
        int e = i - NPIX;
        int c = e / NQ;
        p = 4 + c;
        key = __float_as_uint(qs[e]);
        id = (unsigned)(e - c * NQ);
    }
}

// LDS-privatized radix histogram (global same-address atomics were 222us).
__global__ __launch_bounds__(256) void k_hist(const int* __restrict__ lab,
                       const float* __restrict__ ps,
                       const float* __restrict__ qs, const unsigned* __restrict__ st,
                       unsigned* __restrict__ hist, int level) {
    __shared__ unsigned lh[8 * 2048];
    int tid = threadIdx.x;
    for (int i = tid; i < 8 * 2048; i += 256) lh[i] = 0u;
    __syncthreads();
    for (int i = blockIdx.x * 256 + tid; i < NTOT; i += HBLK * 256) {
        int p; unsigned key, id;
        elem_info(i, lab, ps, qs, p, key, id);
        if (level == 0) {
            atomicAdd(&lh[p * 2048 + (key >> 21)], 1u);
        } else if (level == 1) {
            if ((key >> 21) == (st[p * 8 + 0] >> 21))
                atomicAdd(&lh[p * 2048 + ((key >> 10) & 2047u)], 1u);
        } else {
            if ((key >> 10) == (st[p * 8 + 0] >> 10))
                atomicAdd(&lh[p * 1024 + (key & 1023u)], 1u);
        }
    }
    __syncthreads();
    int nb = (level == 2) ? 8 * 1024 : 8 * 2048;
    for (int i = tid; i < nb; i += 256) {
        unsigned v = lh[i];
        if (v) atomicAdd(&hist[i], v);
    }
}

__global__ void k_scan(const unsigned* __restrict__ hist, unsigned* __restrict__ st,
                       int nbins, int shift, int level) {
    __shared__ unsigned sh[2048];
    __shared__ unsigned segsum[256];
    int p = blockIdx.x;
    int tid = threadIdx.x;
    const unsigned* h = hist + p * nbins;
    int seg = nbins >> 8;
    for (int i = tid; i < nbins; i += 256) sh[i] = h[i];
    __syncthreads();
    unsigned ssum = 0;
    for (int k = 0; k < seg; ++k) ssum += sh[tid * seg + k];
    segsum[tid] = ssum;
    __syncthreads();
    if (tid == 0) {
        unsigned K = (level == 0) ? (unsigned)KSEL : st[p * 8 + 1];
        unsigned cum = 0;
        int s = 255;
        for (; s > 0; --s) { if (cum + segsum[s] >= K) break; cum += segsum[s]; }
        int b = s * seg + seg - 1;
        for (; b > s * seg; --b) { if (cum + sh[b] >= K) break; cum += sh[b]; }
        unsigned krem = (K > cum) ? (K - cum) : 1u;
        if (level == 0)      { st[p * 8 + 0] = ((unsigned)b) << shift; st[p * 8 + 1] = krem; }
        else if (level == 1) { st[p * 8 + 0] |= ((unsigned)b) << shift; st[p * 8 + 1] = krem; }
        else                 { st[p * 8 + 2] = st[p * 8 + 0] | (unsigned)b; st[p * 8 + 3] = krem; }
    }
}

__global__ void k_gather(const int* __restrict__ lab, const float* __restrict__ ps,
                         const float* __restrict__ qs, unsigned* __restrict__ st,
                         unsigned* __restrict__ src, unsigned* __restrict__ eq) {
    int i = blockIdx.x * blockDim.x + threadIdx.x;
    if (i >= NTOT) return;
    int p; unsigned key, id;
    elem_info(i, lab, ps, qs, p, key, id);
    unsigned T = st[p * 8 + 2];
    if (key > T) {
        unsigned slot = atomicAdd(&st[p * 8 + 4], 1u);
        if (slot < KSEL) src[p * KSEL + slot] = id;
    } else if (key == T) {
        unsigned e = atomicAdd(&st[p * 8 + 5], 1u);
        if (e < 4096u) eq[p * 4096 + e] = id;
    }
}

__global__ void k_eqsel(unsigned* __restrict__ st, unsigned* __restrict__ src,
                        unsigned* __restrict__ eq) {
    int p = blockIdx.x;
    if (threadIdx.x != 0) return;
    unsigned take = st[p * 8 + 3];
    unsigned cnt  = st[p * 8 + 4];
    unsigned m    = st[p * 8 + 5]; if (m > 4096u) m = 4096u;
    unsigned* eb = eq + p * 4096;
    for (unsigned k = 0; k < take; ++k) {
        unsigned best = 0xFFFFFFFFu; int bi = -1;
        for (unsigned t = 0; t < m; ++t) if (eb[t] < best) { best = eb[t]; bi = (int)t; }
        if (bi < 0) break;
        eb[bi] = 0xFFFFFFFFu;
        if (cnt + k < KSEL) src[p * KSEL + cnt + k] = best;
    }
}

// gather anchors and convert to bf16 (RNE) row-major [4096][128]
__global__ void k_copy(const unsigned* __restrict__ src, const float* __restrict__ feats,
                       const float* __restrict__ pq, unsigned short* __restrict__ Xab) {
    int row = blockIdx.x;
    int ch = threadIdx.x;
    unsigned s = src[row];
    float v;
    if (row < 2048) {
        s &= (NPIX - 1);                      // safety clamp (no-op when logic correct)
        unsigned bv = s >> 17, r = s & (SPAT - 1);
        v = feats[((size_t)bv * DIMF + ch) * SPAT + r];
    } else {
        if (s >= NQ) s = NQ - 1;              // safety clamp
        int c = (row - 2048) >> 9;
        v = pq[((size_t)(c * NQ + s)) * DIMF + ch];
    }
    unsigned u = __float_as_uint(v);
    unsigned b = (u + 0x7FFFu + ((u >> 16) & 1u)) >> 16;
    Xab[(size_t)row * DIMF + ch] = (unsigned short)b;
}

// ---- MFMA gram helpers ----
// LDS tile layout: 128 rows x 8 chunks of 16B, chunk slot = c ^ (r&7) (bank swizzle)
__device__ __forceinline__ void stage_half(const unsigned short* __restrict__ Xab,
                                           short* lds, int row0, int kk, int tid) {
#pragma unroll
    for (int it = 0; it < 4; ++it) {
        int idx = it * 256 + tid;            // 0..1023 = 128 rows x 8 chunks
        int r = idx >> 3, c = idx & 7;
        uint4 v = *(const uint4*)(Xab + (size_t)(row0 + r) * DIMF + kk * 64 + c * 8);
        *(uint4*)(lds + (r * 8 + (c ^ (r & 7))) * 8) = v;
    }
}

__device__ __forceinline__ short8 frag_ld(const short* lds, int r, int c) {
    return *(const short8*)(lds + (r * 8 + (c ^ (r & 7))) * 8);
}

// pass 1: full 4096x4096 bf16-MFMA gram, online row-max + neg-exp-sum
__global__ __launch_bounds__(256) void k_mm1(const unsigned short* __restrict__ Xab,
                                             float* __restrict__ part) {
    __shared__ short As[8192];   // 128 x 64 bf16 (16 KB)
    __shared__ short Bs[8192];
    int tid = threadIdx.x;
    int row0 = blockIdx.x * 128, col0 = blockIdx.y * 128;
    int w = tid >> 6, lane = tid & 63;
    int wr = w >> 1, wc = w & 1;
    int m_ = lane & 15, q = lane >> 4;

    f32x4 acc[4][4];
#pragma unroll
    for (int rt = 0; rt < 4; ++rt)
#pragma unroll
        for (int ct = 0; ct < 4; ++ct) acc[rt][ct] = (f32x4)0.f;

    for (int kk = 0; kk < 2; ++kk) {
        __syncthreads();
        stage_half(Xab, As, row0, kk, tid);
        stage_half(Xab, Bs, col0, kk, tid);
        __syncthreads();
#pragma unroll
        for (int s0 = 0; s0 < 2; ++s0) {
            short8 af[4], bf[4];
#pragma unroll
            for (int rt = 0; rt < 4; ++rt) af[rt] = frag_ld(As, wr * 64 + rt * 16 + m_, s0 * 4 + q);
#pragma unroll
            for (int ct = 0; ct < 4; ++ct) bf[ct] = frag_ld(Bs, wc * 64 + ct * 16 + m_, s0 * 4 + q);
#pragma unroll
            for (int rt = 0; rt < 4; ++rt)
#pragma unroll
                for (int ct = 0; ct < 4; ++ct)
                    acc[rt][ct] = __builtin_amdgcn_mfma_f32_16x16x32_bf16(af[rt], bf[ct], acc[rt][ct], 0, 0, 0);
        }
    }

    // epilogue: per-row max + neg-sum over this block's 128 cols
    __syncthreads();                 // done reading As/Bs; reuse As as float buf
    float* buf = (float*)As;         // [128 rows][2 wc][2]
#pragma unroll
    for (int rt = 0; rt < 4; ++rt) {
#pragma unroll
        for (int reg = 0; reg < 4; ++reg) {
            int rloc = wr * 64 + rt * 16 + q * 4 + reg;
            int row = row0 + rloc;
            int rcls = (row >> 9) & 3;
            float s[4]; bool ng[4];
#pragma unroll
            for (int ct = 0; ct < 4; ++ct) {
                int col = col0 + wc * 64 + ct * 16 + m_;
                s[ct] = acc[rt][ct][reg] * 10.0f;   // / TEMPERATURE
                ng[ct] = (((col >> 9) & 3) != rcls) || (col == row);  // neg_mask keeps diag
            }
            float mx = fmaxf(fmaxf(s[0], s[1]), fmaxf(s[2], s[3]));
#pragma unroll
            for (int off = 1; off < 16; off <<= 1) mx = fmaxf(mx, __shfl_xor(mx, off, 64));
            float sn = 0.f;
#pragma unroll
            for (int ct = 0; ct < 4; ++ct) if (ng[ct]) sn += __expf(s[ct] - mx);
#pragma unroll
            for (int off = 1; off < 16; off <<= 1) sn += __shfl_xor(sn, off, 64);
            if (m_ == 0) { buf[rloc * 4 + wc * 2] = mx; buf[rloc * 4 + wc * 2 + 1] = sn; }
        }
    }
    __syncthreads();
    if (tid < 128) {
        float m0 = buf[tid * 4], s0 = buf[tid * 4 + 1];
        float m1 = buf[tid * 4 + 2], s1 = buf[tid * 4 + 3];
        float M = fmaxf(m0, m1);
        float SN = s0 * __expf(m0 - M) + s1 * __expf(m1 - M);
        float* o = part + ((size_t)(row0 + tid) * 32 + blockIdx.y) * 2;
        o[0] = M; o[1] = SN;
    }
}

__global__ void k_reduce1(const float* __restrict__ part, float* __restrict__ Mv,
                          float* __restrict__ Ng) {
    int i = blockIdx.x * blockDim.x + threadIdx.x;
    if (i >= NROW) return;
    float M = -1e30f;
    for (int k = 0; k < 32; ++k) M = fmaxf(M, part[((size_t)i * 32 + k) * 2]);
    float SN = 0.f;
    for (int k = 0; k < 32; ++k) {
        float f = __expf(part[((size_t)i * 32 + k) * 2] - M);
        SN += part[((size_t)i * 32 + k) * 2 + 1] * f;
    }
    Mv[i] = M;
    Ng[i] = SN;
}

// pass 2: positives only (each class block: 2 segments x 512 same-class cols).
// Every row has exactly 1023 positives -> whole term reduces to one scalar.
__global__ __launch_bounds__(256) void k_mm2(const unsigned short* __restrict__ Xab,
                                             const float* __restrict__ Mv,
                                             const float* __restrict__ Ng,
                                             float* __restrict__ Ps) {
    __shared__ short As[8192];
    __shared__ short Bs[8192];
    int tid = threadIdx.x;
    int row0 = blockIdx.x * 128;
    int cls = (blockIdx.x >> 2) & 3;
    int j = blockIdx.y;
    int col0 = (j >> 2) * 2048 + cls * 512 + (j & 3) * 128;
    int w = tid >> 6, lane = tid & 63;
    int wr = w >> 1, wc = w & 1;
    int m_ = lane & 15, q = lane >> 4;

    f32x4 acc[4][4];
#pragma unroll
    for (int rt = 0; rt < 4; ++rt)
#pragma unroll
        for (int ct = 0; ct < 4; ++ct) acc[rt][ct] = (f32x4)0.f;

    for (int kk = 0; kk < 2; ++kk) {
        __syncthreads();
        stage_half(Xab, As, row0, kk, tid);
        stage_half(Xab, Bs, col0, kk, tid);
        __syncthreads();
#pragma unroll
        for (int s0 = 0; s0 < 2; ++s0) {
            short8 af[4], bf[4];
#pragma unroll
            for (int rt = 0; rt < 4; ++rt) af[rt] = frag_ld(As, wr * 64 + rt * 16 + m_, s0 * 4 + q);
#pragma unroll
            for (int ct = 0; ct < 4; ++ct) bf[ct] = frag_ld(Bs, wc * 64 + ct * 16 + m_, s0 * 4 + q);
#pragma unroll
            for (int rt = 0; rt < 4; ++rt)
#pragma unroll
                for (int ct = 0; ct < 4; ++ct)
                    acc[rt][ct] = __builtin_amdgcn_mfma_f32_16x16x32_bf16(af[rt], bf[ct], acc[rt][ct], 0, 0, 0);
        }
    }

    float pac = 0.f;
#pragma unroll
    for (int rt = 0; rt < 4; ++rt) {
#pragma unroll
        for (int reg = 0; reg < 4; ++reg) {
            int row = row0 + wr * 64 + rt * 16 + q * 4 + reg;
            float mv = Mv[row], ngv = Ng[row];
#pragma unroll
            for (int ct = 0; ct < 4; ++ct) {
                int col = col0 + wc * 64 + ct * 16 + m_;
                if (col != row) {
                    float t = acc[rt][ct][reg] * 10.0f - mv;
                    pac += t - __logf(__expf(t) + ngv + 1e-10f);
                }
            }
        }
    }
#pragma unroll
    for (int off = 1; off < 64; off <<= 1) pac += __shfl_xor(pac, off, 64);
    if (lane == 0) atomicAdd(Ps, pac);
}

__global__ void k_final(const float* __restrict__ Ps, float* __restrict__ out) {
    out[0] = Ps[0] * (-(10.0f / 7.0f) / (1023.0f * (float)NROW));
}

extern "C" void kernel_launch(void* const* d_in, const int* in_sizes, int n_in,
                              void* d_out, int out_size, void* d_ws, size_t ws_size,
                              hipStream_t stream) {
    const float* feats = (const float*)d_in[0];
    const int*   lab   = (const int*)d_in[1];
    const float* pq    = (const float*)d_in[2];
    const float* ps    = (const float*)d_in[3];
    const float* qs    = (const float*)d_in[4];
    float* out = (float*)d_out;
    char* ws = (char*)d_ws;

    unsigned short* Xab = (unsigned short*)(ws + XAB_OFF);
    float*    Mv  = (float*)(ws + M_OFF);
    float*    Ng  = (float*)(ws + NEG_OFF);
    float*    Pt  = (float*)(ws + PART_OFF);
    unsigned* src = (unsigned*)(ws + SRC_OFF);
    float*    Psum= (float*)(ws + PSUM_OFF);
    unsigned* hA  = (unsigned*)(ws + HA_OFF);
    unsigned* hB  = (unsigned*)(ws + HB_OFF);
    unsigned* hC  = (unsigned*)(ws + HC_OFF);
    unsigned* st  = (unsigned*)(ws + ST_OFF);
    unsigned* eq  = (unsigned*)(ws + EQ_OFF);

    k_zero<<<(ZERO_WORDS + 255) / 256, 256, 0, stream>>>((unsigned*)(ws + PSUM_OFF));

    int hb = (NTOT + 255) / 256;
    k_hist<<<HBLK, 256, 0, stream>>>(lab, ps, qs, st, hA, 0);
    k_scan<<<8, 256, 0, stream>>>(hA, st, 2048, 21, 0);
    k_hist<<<HBLK, 256, 0, stream>>>(lab, ps, qs, st, hB, 1);
    k_scan<<<8, 256, 0, stream>>>(hB, st, 2048, 10, 1);
    k_hist<<<HBLK, 256, 0, stream>>>(lab, ps, qs, st, hC, 2);
    k_scan<<<8, 256, 0, stream>>>(hC, st, 1024, 0, 2);
    k_gather<<<hb, 256, 0, stream>>>(lab, ps, qs, st, src, eq);
    k_eqsel<<<8, 64, 0, stream>>>(st, src, eq);
    k_copy<<<NROW, 128, 0, stream>>>(src, feats, pq, Xab);

    k_mm1<<<dim3(32, 32), 256, 0, stream>>>(Xab, Pt);
    k_reduce1<<<16, 256, 0, stream>>>(Pt, Mv, Ng);
    k_mm2<<<dim3(32, 8), 256, 0, stream>>>(Xab, Mv, Ng, Psum);
    k_final<<<1, 1, 0, stream>>>(Psum, out);
}